// Round 4
// baseline (345.913 us; speedup 1.0000x reference)
//
#include <hip/hip_runtime.h>
#include <hip/hip_bf16.h>

#define B 2
#define N 20000
#define M 4096
#define S 2
#define K 25
#define J 64
#define KJ (K*J)        // 1600
#define TC 32           // MLP column tile

#define C1    10176     // phase-0 rows in LDS = 162816 B (<= 163840); phase 1 = 9824 rows
#define GPB   64        // groups per block
#define NTH   1024      // 16 single-wave teams

typedef int   iv4 __attribute__((ext_vector_type(4)));
typedef float fv4 __attribute__((ext_vector_type(4)));

template<int CTRL>
__device__ __forceinline__ float dppadd(float x) {
    // x + value-from-partner-lane per DPP ctrl (all rows/banks, bound_ctrl=1)
    return x + __int_as_float(
        __builtin_amdgcn_update_dpp(0, __float_as_int(x), CTRL, 0xF, 0xF, true));
}

// ---------------- Kernel A: prep ----------------
__global__ __launch_bounds__(256) void prep_kernel(
    const float* __restrict__ xyz, const float* __restrict__ feature,
    const float* __restrict__ new_xyz, const float* __restrict__ conv_w,
    const float* __restrict__ w0, const float* __restrict__ w1,
    __hip_bfloat16* __restrict__ xfh, float* __restrict__ conv_wT,
    float* __restrict__ w0T, float* __restrict__ w1T,
    float* __restrict__ wsum, float* __restrict__ out_newxyz) {
    const int T1 = B * N * 8;     // 320000
    const int T2 = 208 * 64;      // 13312 (52 float4-rows x 64 o)
    const int T3 = B * M * 3;     // 24576
    const int T4 = 128 * 128;     // 16384
    const int T5 = 128 * 256;     // 32768
    const int T6 = 128;           // wsum[c][o], c in {0,1}
    int e = blockIdx.x * blockDim.x + threadIdx.x;
    if (e < T1) {
        int r = e >> 3, t = e & 7;
        float v = (t < 2) ? xyz[r * 3 + t] : feature[r * 6 + (t - 2)];
        xfh[e] = __float2bfloat16(v);
    } else if (e < T1 + T2) {
        // float4-packed conv weights: cw4[i4][o][t], i = i4*4+t, i = k*8+c
        int e2 = e - T1;
        int i4 = e2 >> 8;          // [0,52)
        int rem = e2 & 255;
        int o = rem >> 2, t = rem & 3;
        int i = i4 * 4 + t;
        conv_wT[e2] = (i < 200) ? conv_w[o * 200 + (i & 7) * 25 + (i >> 3)] : 0.f;
    } else if (e < T1 + T2 + T3) {
        int e3 = e - T1 - T2;
        out_newxyz[e3] = new_xyz[e3];
    } else if (e < T1 + T2 + T3 + T4) {
        int e4 = e - T1 - T2 - T3;
        int c = e4 >> 7, o = e4 & 127;          // w0T[c][o]
        w0T[e4] = w0[o * 128 + c];
    } else if (e < T1 + T2 + T3 + T4 + T5) {
        int e5 = e - T1 - T2 - T3 - T4;
        int c = e5 >> 8, o = e5 & 255;          // w1T[c][o]
        w1T[e5] = w1[o * 128 + c];
    } else if (e < T1 + T2 + T3 + T4 + T5 + T6) {
        // center-correction weights: wsum[sel*64+o] = sum_k conv_w[o, sel, k]
        int e6 = e - T1 - T2 - T3 - T4 - T5;
        int o = e6 & 63, sel = e6 >> 6;
        float s = 0.f;
        for (int k = 0; k < 25; ++k) s += conv_w[o * 200 + sel * 25 + k];
        wsum[e6] = s;
    }
}

// ---------------- Kernel B: two-phase all-LDS gather + conv + relu ----------------
// 256 blocks x 64 groups, 16 single-wave teams. The 320KB per-b xf table is
// processed in TWO LDS phases (rows [0,C1) then [C1,N)); every gather is a
// ds_read_b128 -- zero random L2 requests. Conv partials acc2[4] stay in
// registers across the phase boundary (conv is linear); the center subtraction
// folds into precomputed wsum. j-reduction is pure-VALU DPP (xor1/xor2/
// half-mirror: 7-q == q^7 for 3-bit q). Conv weight loads amortized x4 groups.
// Cost: idx/weight streamed twice (nt, mostly L3-hit). Request budget ~10M.
__global__ __launch_bounds__(NTH, 4) void gather_conv_kernel(
    const int* __restrict__ idx, const float* __restrict__ weight,
    const float* __restrict__ new_xyz, const uint4* __restrict__ xfh,
    const float* __restrict__ conv_wT, const float* __restrict__ conv_b,
    const float* __restrict__ wsum, float* __restrict__ xmid) {
    __shared__ uint4 chunk[C1];   // 162816 B

    const int tid = threadIdx.x;
    const int g0  = blockIdx.x * GPB;          // 64 consecutive g: same (s,b)
    const int b   = (g0 >> 12) & (B - 1);
    const uint4* xfb = xfh + (size_t)b * N;

    const int team = tid >> 6;                 // 16 teams, one wave each
    const int lane = tid & 63;
    const float4* cw4 = (const float4*)conv_wT;

    float acc2[4] = {0.f, 0.f, 0.f, 0.f};      // conv partial per group (o = lane)

    #pragma unroll 1
    for (int ph = 0; ph < 2; ++ph) {
        const int cbase = ph ? C1 : 0;
        const int csize = ph ? (N - C1) : C1;
        if (ph) __syncthreads();               // everyone done with prev chunk
        for (int r = tid; r < csize; r += NTH) chunk[r] = xfb[cbase + r];
        __syncthreads();

        // passes p=0..2: k = p*8 + (lane>>3); pass p=3: k=24 on lanes 0..7
        #pragma unroll 1
        for (int p = 0; p < 4; ++p) {
            const int myk  = p * 8 + (lane >> 3);
            const int mykc = (myk > 24) ? 24 : myk;    // clamped: no divergence
            const bool act = (p < 3) || (lane < 8);
            float ar[4][8];                    // reduced nf per group

            #pragma unroll
            for (int u = 0; u < 4; ++u) {
                const size_t base = (size_t)(g0 + team * 4 + u) * KJ
                                  + (size_t)mykc * J + (lane & 7) * 8;
                const iv4 ia = __builtin_nontemporal_load((const iv4*)(idx + base));
                const iv4 ib = __builtin_nontemporal_load((const iv4*)(idx + base) + 1);
                const fv4 wa = __builtin_nontemporal_load((const fv4*)(weight + base));
                const fv4 wb = __builtin_nontemporal_load((const fv4*)(weight + base) + 1);
                const int   ids[8] = {ia.x, ia.y, ia.z, ia.w, ib.x, ib.y, ib.z, ib.w};
                const float wsv[8] = {wa.x, wa.y, wa.z, wa.w, wb.x, wb.y, wb.z, wb.w};

                uint4 rr[8];
                float we[8];
                #pragma unroll
                for (int j = 0; j < 8; ++j) {
                    const unsigned rel = (unsigned)(ids[j] - cbase);
                    const bool inr = (rel < (unsigned)csize) && act;
                    rr[j] = chunk[inr ? rel : 0u];     // OOR lanes: broadcast row 0
                    we[j] = inr ? wsv[j] : 0.f;
                }

                float acc[8] = {0.f,0.f,0.f,0.f,0.f,0.f,0.f,0.f};
                #pragma unroll
                for (int j = 0; j < 8; ++j) {
                    const uint4 r = rr[j];
                    const float w = we[j];
                    acc[0] = fmaf(w, __uint_as_float(r.x << 16),         acc[0]);
                    acc[1] = fmaf(w, __uint_as_float(r.x & 0xffff0000u), acc[1]);
                    acc[2] = fmaf(w, __uint_as_float(r.y << 16),         acc[2]);
                    acc[3] = fmaf(w, __uint_as_float(r.y & 0xffff0000u), acc[3]);
                    acc[4] = fmaf(w, __uint_as_float(r.z << 16),         acc[4]);
                    acc[5] = fmaf(w, __uint_as_float(r.z & 0xffff0000u), acc[5]);
                    acc[6] = fmaf(w, __uint_as_float(r.w << 16),         acc[6]);
                    acc[7] = fmaf(w, __uint_as_float(r.w & 0xffff0000u), acc[7]);
                }
                // 8-lane sum, pure VALU: quad xor1, quad xor2, row_half_mirror
                #pragma unroll
                for (int c = 0; c < 8; ++c) {
                    float x = acc[c];
                    x = dppadd<0xB1>(x);       // quad_perm (1,0,3,2)  = xor 1
                    x = dppadd<0x4E>(x);       // quad_perm (2,3,0,1)  = xor 2
                    x = dppadd<0x141>(x);      // row_half_mirror: q^7 completes 8-sum
                    ar[u][c] = x;
                }
            }

            // conv: weights loaded once per (p,kk), used by all 4 groups
            const int nk = (p < 3) ? 8 : 1;
            #pragma unroll
            for (int kk = 0; kk < 8; ++kk) {
                if (kk < nk) {
                    const float4 w4a = cw4[(p * 8 + kk) * 128 + lane];
                    const float4 w4b = cw4[(p * 8 + kk) * 128 + 64 + lane];
                    #pragma unroll
                    for (int u = 0; u < 4; ++u) {
                        acc2[u] = fmaf(w4a.x, __shfl(ar[u][0], kk * 8, 64), acc2[u]);
                        acc2[u] = fmaf(w4a.y, __shfl(ar[u][1], kk * 8, 64), acc2[u]);
                        acc2[u] = fmaf(w4a.z, __shfl(ar[u][2], kk * 8, 64), acc2[u]);
                        acc2[u] = fmaf(w4a.w, __shfl(ar[u][3], kk * 8, 64), acc2[u]);
                        acc2[u] = fmaf(w4b.x, __shfl(ar[u][4], kk * 8, 64), acc2[u]);
                        acc2[u] = fmaf(w4b.y, __shfl(ar[u][5], kk * 8, 64), acc2[u]);
                        acc2[u] = fmaf(w4b.z, __shfl(ar[u][6], kk * 8, 64), acc2[u]);
                        acc2[u] = fmaf(w4b.w, __shfl(ar[u][7], kk * 8, 64), acc2[u]);
                    }
                }
            }
        }
    }

    // epilogue: bias + center correction + relu + store
    const float bo  = conv_b[lane];
    const float wsx = wsum[lane];
    const float wsy = wsum[64 + lane];
    #pragma unroll
    for (int u = 0; u < 4; ++u) {
        const int g = g0 + team * 4 + u;
        const int m = g & (M - 1);
        const int s = g >> 13;
        const float cx = new_xyz[(b * M + m) * 3 + 0];
        const float cy = new_xyz[(b * M + m) * 3 + 1];
        const float v = acc2[u] + bo - cx * wsx - cy * wsy;
        xmid[((size_t)(b * M + m)) * 128 + s * 64 + lane] = fmaxf(v, 0.f);
    }
}

// ---------------- Kernel C0: MLP0 + relu (in-place xmid [col][128]) ----------------
__global__ __launch_bounds__(256) void mlp0_kernel(
    float* __restrict__ xmid,
    const float* __restrict__ w0T, const float* __restrict__ b0) {
    __shared__ float ws[128 * 128];   // 64 KB, [c][o]
    __shared__ float xs[128 * 32];    // 16 KB, [c][col]

    int tid = threadIdx.x;
    int col0 = blockIdx.x * TC;

    {
        const float4* w4 = (const float4*)w0T;
        float4* ws4 = (float4*)ws;
        #pragma unroll
        for (int i = 0; i < 16; ++i) ws4[tid + 256 * i] = w4[tid + 256 * i];
    }
    {
        const float4* xm4 = (const float4*)(xmid + (size_t)col0 * 128);
        #pragma unroll
        for (int r = tid; r < 1024; r += 256) {
            int lc = r >> 5, c4 = r & 31;
            float4 v = xm4[lc * 32 + c4];
            int c = c4 * 4;
            xs[(c + 0) * 32 + lc] = v.x;
            xs[(c + 1) * 32 + lc] = v.y;
            xs[(c + 2) * 32 + lc] = v.z;
            xs[(c + 3) * 32 + lc] = v.w;
        }
    }
    __syncthreads();

    int og = tid >> 3, cg = tid & 7;
    int o0 = og * 4, lc0 = cg * 4;
    float acc[4][4];
    #pragma unroll
    for (int i = 0; i < 4; ++i) {
        float bv = b0[o0 + i];
        #pragma unroll
        for (int u = 0; u < 4; ++u) acc[i][u] = bv;
    }
    for (int c = 0; c < 128; ++c) {
        float4 xv = *(const float4*)&xs[c * 32 + lc0];
        float4 wv = *(const float4*)&ws[c * 128 + o0];
        acc[0][0] = fmaf(wv.x, xv.x, acc[0][0]);
        acc[0][1] = fmaf(wv.x, xv.y, acc[0][1]);
        acc[0][2] = fmaf(wv.x, xv.z, acc[0][2]);
        acc[0][3] = fmaf(wv.x, xv.w, acc[0][3]);
        acc[1][0] = fmaf(wv.y, xv.x, acc[1][0]);
        acc[1][1] = fmaf(wv.y, xv.y, acc[1][1]);
        acc[1][2] = fmaf(wv.y, xv.z, acc[1][2]);
        acc[1][3] = fmaf(wv.y, xv.w, acc[1][3]);
        acc[2][0] = fmaf(wv.z, xv.x, acc[2][0]);
        acc[2][1] = fmaf(wv.z, xv.y, acc[2][1]);
        acc[2][2] = fmaf(wv.z, xv.z, acc[2][2]);
        acc[2][3] = fmaf(wv.z, xv.w, acc[2][3]);
        acc[3][0] = fmaf(wv.w, xv.x, acc[3][0]);
        acc[3][1] = fmaf(wv.w, xv.y, acc[3][1]);
        acc[3][2] = fmaf(wv.w, xv.z, acc[3][2]);
        acc[3][3] = fmaf(wv.w, xv.w, acc[3][3]);
    }
    #pragma unroll
    for (int u = 0; u < 4; ++u) {
        float4 v = make_float4(fmaxf(acc[0][u], 0.f), fmaxf(acc[1][u], 0.f),
                               fmaxf(acc[2][u], 0.f), fmaxf(acc[3][u], 0.f));
        *(float4*)&xmid[(size_t)(col0 + lc0 + u) * 128 + o0] = v;
    }
}

// ---------------- Kernel C1: MLP1 + relu + store (o-split) ----------------
__global__ __launch_bounds__(256) void mlp1_kernel(
    const float* __restrict__ xmid,
    const float* __restrict__ w1T, const float* __restrict__ b1,
    float* __restrict__ out_rf) {
    __shared__ float ws[128 * 128];   // 64 KB, [c][o-half]
    __shared__ float xs[128 * 32];    // 16 KB

    int tid = threadIdx.x;
    int bx = blockIdx.x;
    int col0 = (bx >> 1) * TC;
    int oH = (bx & 1) * 128;

    {
        for (int i = tid; i < 4096; i += 256) {
            int c = i >> 5, q = i & 31;
            *(float4*)&ws[c * 128 + q * 4] = *(const float4*)&w1T[c * 256 + oH + q * 4];
        }
    }
    {
        const float4* xm4 = (const float4*)(xmid + (size_t)col0 * 128);
        #pragma unroll
        for (int r = tid; r < 1024; r += 256) {
            int lc = r >> 5, c4 = r & 31;
            float4 v = xm4[lc * 32 + c4];
            int c = c4 * 4;
            xs[(c + 0) * 32 + lc] = v.x;
            xs[(c + 1) * 32 + lc] = v.y;
            xs[(c + 2) * 32 + lc] = v.z;
            xs[(c + 3) * 32 + lc] = v.w;
        }
    }
    __syncthreads();

    int og = tid >> 3, cg = tid & 7;
    int o0 = og * 4, lc0 = cg * 4;
    float acc[4][4];
    #pragma unroll
    for (int i = 0; i < 4; ++i) {
        float bv = b1[oH + o0 + i];
        #pragma unroll
        for (int u = 0; u < 4; ++u) acc[i][u] = bv;
    }
    for (int c = 0; c < 128; ++c) {
        float4 xv = *(const float4*)&xs[c * 32 + lc0];
        float4 wv = *(const float4*)&ws[c * 128 + o0];
        acc[0][0] = fmaf(wv.x, xv.x, acc[0][0]);
        acc[0][1] = fmaf(wv.x, xv.y, acc[0][1]);
        acc[0][2] = fmaf(wv.x, xv.z, acc[0][2]);
        acc[0][3] = fmaf(wv.x, xv.w, acc[0][3]);
        acc[1][0] = fmaf(wv.y, xv.x, acc[1][0]);
        acc[1][1] = fmaf(wv.y, xv.y, acc[1][1]);
        acc[1][2] = fmaf(wv.y, xv.z, acc[1][2]);
        acc[1][3] = fmaf(wv.y, xv.w, acc[1][3]);
        acc[2][0] = fmaf(wv.z, xv.x, acc[2][0]);
        acc[2][1] = fmaf(wv.z, xv.y, acc[2][1]);
        acc[2][2] = fmaf(wv.z, xv.z, acc[2][2]);
        acc[2][3] = fmaf(wv.z, xv.w, acc[2][3]);
        acc[3][0] = fmaf(wv.w, xv.x, acc[3][0]);
        acc[3][1] = fmaf(wv.w, xv.y, acc[3][1]);
        acc[3][2] = fmaf(wv.w, xv.z, acc[3][2]);
        acc[3][3] = fmaf(wv.w, xv.w, acc[3][3]);
    }
    #pragma unroll
    for (int u = 0; u < 4; ++u) {
        float4 v = make_float4(fmaxf(acc[0][u], 0.f), fmaxf(acc[1][u], 0.f),
                               fmaxf(acc[2][u], 0.f), fmaxf(acc[3][u], 0.f));
        *(float4*)&out_rf[(size_t)(col0 + lc0 + u) * 256 + oH + o0] = v;
    }
}

extern "C" void kernel_launch(void* const* d_in, const int* in_sizes, int n_in,
                              void* d_out, int out_size, void* d_ws, size_t ws_size,
                              hipStream_t stream) {
    const float* xyz     = (const float*)d_in[0];
    const float* feature = (const float*)d_in[1];
    const float* new_xyz = (const float*)d_in[2];
    const int*   idx     = (const int*)  d_in[3];
    const float* weight  = (const float*)d_in[4];
    const float* conv_w  = (const float*)d_in[5];
    const float* conv_b  = (const float*)d_in[6];
    const float* mlp_w0  = (const float*)d_in[7];
    const float* mlp_b0  = (const float*)d_in[8];
    const float* mlp_w1  = (const float*)d_in[9];
    const float* mlp_b1  = (const float*)d_in[10];

    float* out    = (float*)d_out;
    float* out_rf = out + (size_t)B * M * 3;

    float* wsf = (float*)d_ws;
    __hip_bfloat16* xfh = (__hip_bfloat16*)wsf;  // 320000 bf16
    float* conv_wT = wsf + 160000;               // 13312
    float* xmid    = conv_wT + 13312;            // B*M*128, [col][c]
    float* w0T     = xmid + 1048576;             // 16384
    float* w1T     = w0T + 16384;                // 32768
    float* wsum    = w1T + 32768;                // 128

    {
        int total = 320000 + 13312 + 24576 + 16384 + 32768 + 128;
        int blocks = (total + 255) / 256;
        prep_kernel<<<blocks, 256, 0, stream>>>(xyz, feature, new_xyz, conv_w,
                                                mlp_w0, mlp_w1,
                                                xfh, conv_wT, w0T, w1T, wsum, out);
    }
    {
        int blocks = (S * B * M) / GPB;         // 256
        gather_conv_kernel<<<blocks, NTH, 0, stream>>>(idx, weight, new_xyz,
                                                       (const uint4*)xfh,
                                                       conv_wT, conv_b, wsum, xmid);
    }
    {
        mlp0_kernel<<<(B * M) / TC, 256, 0, stream>>>(xmid, w0T, mlp_b0);
    }
    {
        mlp1_kernel<<<2 * (B * M) / TC, 256, 0, stream>>>(xmid, w1T, mlp_b1, out_rf);
    }
}

// Round 5
// 324.879 us; speedup vs baseline: 1.0647x; 1.0647x over previous
//
#include <hip/hip_runtime.h>
#include <hip/hip_bf16.h>

#define B 2
#define N 20000
#define M 4096
#define S 2
#define K 25
#define J 64
#define KJ (K*J)        // 1600
#define TC 32           // MLP column tile

#define GPB   64        // groups per block-pair
#define NTH   1024      // 16 single-wave teams

typedef int   iv4 __attribute__((ext_vector_type(4)));
typedef float fv4 __attribute__((ext_vector_type(4)));

template<int CTRL>
__device__ __forceinline__ float dppadd(float x) {
    // x + value-from-partner-lane per DPP ctrl (all rows/banks, bound_ctrl=1)
    return x + __int_as_float(
        __builtin_amdgcn_update_dpp(0, __float_as_int(x), CTRL, 0xF, 0xF, true));
}
__device__ __forceinline__ float red8(float x) {
    x = dppadd<0xB1>(x);       // quad_perm xor1
    x = dppadd<0x4E>(x);       // quad_perm xor2
    x = dppadd<0x141>(x);      // row_half_mirror: q^7 completes 8-lane sum
    return x;
}

// ---------------- Kernel A: prep ----------------
// xf stored as TWO 8-byte channel planes per b: plane0 = c0..3 (x,y,f0,f1),
// plane1 = c4..7 (f2..f5). Each plane = 160000 B -> one whole plane fits LDS.
__global__ __launch_bounds__(256) void prep_kernel(
    const float* __restrict__ xyz, const float* __restrict__ feature,
    const float* __restrict__ new_xyz, const float* __restrict__ conv_w,
    const float* __restrict__ w0, const float* __restrict__ w1,
    __hip_bfloat16* __restrict__ xfh, float* __restrict__ conv_wT,
    float* __restrict__ w0T, float* __restrict__ w1T,
    float* __restrict__ wsum, float* __restrict__ out_newxyz) {
    const int T1 = B * N * 8;     // 320000
    const int T2 = 208 * 64;      // 13312 (52 float4-rows x 64 o)
    const int T3 = B * M * 3;     // 24576
    const int T4 = 128 * 128;     // 16384
    const int T5 = 128 * 256;     // 32768
    const int T6 = 128;           // wsum[c][o], c in {0,1}
    int e = blockIdx.x * blockDim.x + threadIdx.x;
    if (e < T1) {
        int r = e >> 3, t = e & 7;          // r = global row, t = channel
        int b = r / N, rr = r - b * N;
        int plane = t >> 2, tt = t & 3;
        float v = (t < 2) ? xyz[r * 3 + t] : feature[r * 6 + (t - 2)];
        xfh[((size_t)(b * 2 + plane) * N + rr) * 4 + tt] = __float2bfloat16(v);
    } else if (e < T1 + T2) {
        // float4-packed conv weights: cw4[i4][o][t], i = i4*4+t, i = k*8+c
        int e2 = e - T1;
        int i4 = e2 >> 8;          // [0,52)
        int rem = e2 & 255;
        int o = rem >> 2, t = rem & 3;
        int i = i4 * 4 + t;
        conv_wT[e2] = (i < 200) ? conv_w[o * 200 + (i & 7) * 25 + (i >> 3)] : 0.f;
    } else if (e < T1 + T2 + T3) {
        int e3 = e - T1 - T2;
        out_newxyz[e3] = new_xyz[e3];
    } else if (e < T1 + T2 + T3 + T4) {
        int e4 = e - T1 - T2 - T3;
        int c = e4 >> 7, o = e4 & 127;          // w0T[c][o]
        w0T[e4] = w0[o * 128 + c];
    } else if (e < T1 + T2 + T3 + T4 + T5) {
        int e5 = e - T1 - T2 - T3 - T4;
        int c = e5 >> 8, o = e5 & 255;          // w1T[c][o]
        w1T[e5] = w1[o * 128 + c];
    } else if (e < T1 + T2 + T3 + T4 + T5 + T6) {
        // center-correction weights: wsum[sel*64+o] = sum_k conv_w[o, sel, k]
        int e6 = e - T1 - T2 - T3 - T4 - T5;
        int o = e6 & 63, sel = e6 >> 6;
        float s = 0.f;
        for (int k = 0; k < 25; ++k) s += conv_w[o * 200 + sel * 25 + k];
        wsum[e6] = s;
    }
}

// ---------------- Kernel B: channel-split all-LDS gather + half-conv ----------------
// 512 blocks = 256 group-sets x 2 channel-planes. Each block stages its WHOLE
// 8B-row plane (20000 rows = 160000 B) in LDS: every gather is one unmasked
// ds_read_b64 -- no range check, no zeroed-weight waste, single-pass VALU.
// Half-conv partials acc2[4] stay in registers; plane-0 block adds bias +
// center correction (wsum fold); mlp0 sums the two partials + relu.
__global__ __launch_bounds__(NTH, 4) void gather_conv_kernel(
    const int* __restrict__ idx, const float* __restrict__ weight,
    const float* __restrict__ new_xyz, const uint2* __restrict__ xfp,
    const float* __restrict__ conv_wT, const float* __restrict__ conv_b,
    const float* __restrict__ wsum,
    float* __restrict__ xmidA, float* __restrict__ xmidB) {
    __shared__ uint2 chunk[N];   // 160000 B

    const int bid   = blockIdx.x;
    const int plane = bid & 1;
    const int g0    = (bid >> 1) * GPB;        // 64 consecutive g: same (s,b)
    const int b     = (g0 >> 12) & (B - 1);
    const uint2* src = xfp + (size_t)(b * 2 + plane) * N;

    const int tid = threadIdx.x;
    for (int r = tid; r < N; r += NTH) chunk[r] = src[r];
    __syncthreads();

    const int team = tid >> 6;                 // 16 teams, one wave each
    const int lane = tid & 63;
    const float4* cw4 = (const float4*)conv_wT;
    const int cwo = plane * 64 + lane;         // plane0: c0..3, plane1: c4..7

    float acc2[4] = {0.f, 0.f, 0.f, 0.f};      // half-conv partial per group (o = lane)

    // passes p=0..2: k = p*8 + (lane>>3); pass p=3: k=24 (lanes 8..63 compute
    // duplicates of k=24 that are simply never read by the conv stage)
    #pragma unroll 1
    for (int p = 0; p < 4; ++p) {
        const int myk  = p * 8 + (lane >> 3);
        const int mykc = (myk > 24) ? 24 : myk;
        float ar[4][4];                        // reduced nf (4 channels) per group

        #pragma unroll
        for (int u = 0; u < 4; ++u) {
            const size_t base = (size_t)(g0 + team * 4 + u) * KJ
                              + (size_t)mykc * J + (lane & 7) * 8;
            const iv4 ia = __builtin_nontemporal_load((const iv4*)(idx + base));
            const iv4 ib = __builtin_nontemporal_load((const iv4*)(idx + base) + 1);
            const fv4 wa = __builtin_nontemporal_load((const fv4*)(weight + base));
            const fv4 wb = __builtin_nontemporal_load((const fv4*)(weight + base) + 1);
            const int   ids[8] = {ia.x, ia.y, ia.z, ia.w, ib.x, ib.y, ib.z, ib.w};
            const float wsv[8] = {wa.x, wa.y, wa.z, wa.w, wb.x, wb.y, wb.z, wb.w};

            float a0 = 0.f, a1 = 0.f, a2 = 0.f, a3 = 0.f;
            #pragma unroll
            for (int j = 0; j < 8; ++j) {
                const uint2 v = chunk[ids[j]];
                const float w = wsv[j];
                a0 = fmaf(w, __uint_as_float(v.x << 16),         a0);
                a1 = fmaf(w, __uint_as_float(v.x & 0xffff0000u), a1);
                a2 = fmaf(w, __uint_as_float(v.y << 16),         a2);
                a3 = fmaf(w, __uint_as_float(v.y & 0xffff0000u), a3);
            }
            ar[u][0] = red8(a0);
            ar[u][1] = red8(a1);
            ar[u][2] = red8(a2);
            ar[u][3] = red8(a3);
        }

        // conv: one float4 of weights per (p,kk,plane), readlane broadcast
        const int nk = (p < 3) ? 8 : 1;
        #pragma unroll
        for (int kk = 0; kk < 8; ++kk) {
            if (kk < nk) {
                const float4 w4 = cw4[(size_t)(p * 8 + kk) * 128 + cwo];
                #pragma unroll
                for (int u = 0; u < 4; ++u) {
                    acc2[u] = fmaf(w4.x, __shfl(ar[u][0], kk * 8, 64), acc2[u]);
                    acc2[u] = fmaf(w4.y, __shfl(ar[u][1], kk * 8, 64), acc2[u]);
                    acc2[u] = fmaf(w4.z, __shfl(ar[u][2], kk * 8, 64), acc2[u]);
                    acc2[u] = fmaf(w4.w, __shfl(ar[u][3], kk * 8, 64), acc2[u]);
                }
            }
        }
    }

    if (plane == 0) {
        const float bo  = conv_b[lane];
        const float wsx = wsum[lane];
        const float wsy = wsum[64 + lane];
        #pragma unroll
        for (int u = 0; u < 4; ++u) {
            const int g = g0 + team * 4 + u;
            const int m = g & (M - 1);
            const int s = g >> 13;
            const float cx = new_xyz[(b * M + m) * 3 + 0];
            const float cy = new_xyz[(b * M + m) * 3 + 1];
            xmidA[((size_t)(b * M + m)) * 128 + s * 64 + lane]
                = acc2[u] + bo - cx * wsx - cy * wsy;
        }
    } else {
        #pragma unroll
        for (int u = 0; u < 4; ++u) {
            const int g = g0 + team * 4 + u;
            const int m = g & (M - 1);
            const int s = g >> 13;
            xmidB[((size_t)(b * M + m)) * 128 + s * 64 + lane] = acc2[u];
        }
    }
}

// ---------------- Kernel C0: MLP0, sums plane partials + relu, writes xmidA ----------------
__global__ __launch_bounds__(256) void mlp0_kernel(
    float* __restrict__ xmidA, const float* __restrict__ xmidB,
    const float* __restrict__ w0T, const float* __restrict__ b0) {
    __shared__ float ws[128 * 128];   // 64 KB, [c][o]
    __shared__ float xs[128 * 32];    // 16 KB, [c][col]

    int tid = threadIdx.x;
    int col0 = blockIdx.x * TC;

    {
        const float4* w4 = (const float4*)w0T;
        float4* ws4 = (float4*)ws;
        #pragma unroll
        for (int i = 0; i < 16; ++i) ws4[tid + 256 * i] = w4[tid + 256 * i];
    }
    {
        const float4* xa4 = (const float4*)(xmidA + (size_t)col0 * 128);
        const float4* xb4 = (const float4*)(xmidB + (size_t)col0 * 128);
        #pragma unroll
        for (int r = tid; r < 1024; r += 256) {
            int lc = r >> 5, c4 = r & 31;
            float4 va = xa4[lc * 32 + c4];
            float4 vb = xb4[lc * 32 + c4];
            int c = c4 * 4;
            xs[(c + 0) * 32 + lc] = fmaxf(va.x + vb.x, 0.f);
            xs[(c + 1) * 32 + lc] = fmaxf(va.y + vb.y, 0.f);
            xs[(c + 2) * 32 + lc] = fmaxf(va.z + vb.z, 0.f);
            xs[(c + 3) * 32 + lc] = fmaxf(va.w + vb.w, 0.f);
        }
    }
    __syncthreads();

    int og = tid >> 3, cg = tid & 7;
    int o0 = og * 4, lc0 = cg * 4;
    float acc[4][4];
    #pragma unroll
    for (int i = 0; i < 4; ++i) {
        float bv = b0[o0 + i];
        #pragma unroll
        for (int u = 0; u < 4; ++u) acc[i][u] = bv;
    }
    for (int c = 0; c < 128; ++c) {
        float4 xv = *(const float4*)&xs[c * 32 + lc0];
        float4 wv = *(const float4*)&ws[c * 128 + o0];
        acc[0][0] = fmaf(wv.x, xv.x, acc[0][0]);
        acc[0][1] = fmaf(wv.x, xv.y, acc[0][1]);
        acc[0][2] = fmaf(wv.x, xv.z, acc[0][2]);
        acc[0][3] = fmaf(wv.x, xv.w, acc[0][3]);
        acc[1][0] = fmaf(wv.y, xv.x, acc[1][0]);
        acc[1][1] = fmaf(wv.y, xv.y, acc[1][1]);
        acc[1][2] = fmaf(wv.y, xv.z, acc[1][2]);
        acc[1][3] = fmaf(wv.y, xv.w, acc[1][3]);
        acc[2][0] = fmaf(wv.z, xv.x, acc[2][0]);
        acc[2][1] = fmaf(wv.z, xv.y, acc[2][1]);
        acc[2][2] = fmaf(wv.z, xv.z, acc[2][2]);
        acc[2][3] = fmaf(wv.z, xv.w, acc[2][3]);
        acc[3][0] = fmaf(wv.w, xv.x, acc[3][0]);
        acc[3][1] = fmaf(wv.w, xv.y, acc[3][1]);
        acc[3][2] = fmaf(wv.w, xv.z, acc[3][2]);
        acc[3][3] = fmaf(wv.w, xv.w, acc[3][3]);
    }
    #pragma unroll
    for (int u = 0; u < 4; ++u) {
        float4 v = make_float4(fmaxf(acc[0][u], 0.f), fmaxf(acc[1][u], 0.f),
                               fmaxf(acc[2][u], 0.f), fmaxf(acc[3][u], 0.f));
        *(float4*)&xmidA[(size_t)(col0 + lc0 + u) * 128 + o0] = v;
    }
}

// ---------------- Kernel C1: MLP1 + relu + store (o-split) ----------------
__global__ __launch_bounds__(256) void mlp1_kernel(
    const float* __restrict__ xmid,
    const float* __restrict__ w1T, const float* __restrict__ b1,
    float* __restrict__ out_rf) {
    __shared__ float ws[128 * 128];   // 64 KB, [c][o-half]
    __shared__ float xs[128 * 32];    // 16 KB

    int tid = threadIdx.x;
    int bx = blockIdx.x;
    int col0 = (bx >> 1) * TC;
    int oH = (bx & 1) * 128;

    {
        for (int i = tid; i < 4096; i += 256) {
            int c = i >> 5, q = i & 31;
            *(float4*)&ws[c * 128 + q * 4] = *(const float4*)&w1T[c * 256 + oH + q * 4];
        }
    }
    {
        const float4* xm4 = (const float4*)(xmid + (size_t)col0 * 128);
        #pragma unroll
        for (int r = tid; r < 1024; r += 256) {
            int lc = r >> 5, c4 = r & 31;
            float4 v = xm4[lc * 32 + c4];
            int c = c4 * 4;
            xs[(c + 0) * 32 + lc] = v.x;
            xs[(c + 1) * 32 + lc] = v.y;
            xs[(c + 2) * 32 + lc] = v.z;
            xs[(c + 3) * 32 + lc] = v.w;
        }
    }
    __syncthreads();

    int og = tid >> 3, cg = tid & 7;
    int o0 = og * 4, lc0 = cg * 4;
    float acc[4][4];
    #pragma unroll
    for (int i = 0; i < 4; ++i) {
        float bv = b1[oH + o0 + i];
        #pragma unroll
        for (int u = 0; u < 4; ++u) acc[i][u] = bv;
    }
    for (int c = 0; c < 128; ++c) {
        float4 xv = *(const float4*)&xs[c * 32 + lc0];
        float4 wv = *(const float4*)&ws[c * 128 + o0];
        acc[0][0] = fmaf(wv.x, xv.x, acc[0][0]);
        acc[0][1] = fmaf(wv.x, xv.y, acc[0][1]);
        acc[0][2] = fmaf(wv.x, xv.z, acc[0][2]);
        acc[0][3] = fmaf(wv.x, xv.w, acc[0][3]);
        acc[1][0] = fmaf(wv.y, xv.x, acc[1][0]);
        acc[1][1] = fmaf(wv.y, xv.y, acc[1][1]);
        acc[1][2] = fmaf(wv.y, xv.z, acc[1][2]);
        acc[1][3] = fmaf(wv.y, xv.w, acc[1][3]);
        acc[2][0] = fmaf(wv.z, xv.x, acc[2][0]);
        acc[2][1] = fmaf(wv.z, xv.y, acc[2][1]);
        acc[2][2] = fmaf(wv.z, xv.z, acc[2][2]);
        acc[2][3] = fmaf(wv.z, xv.w, acc[2][3]);
        acc[3][0] = fmaf(wv.w, xv.x, acc[3][0]);
        acc[3][1] = fmaf(wv.w, xv.y, acc[3][1]);
        acc[3][2] = fmaf(wv.w, xv.z, acc[3][2]);
        acc[3][3] = fmaf(wv.w, xv.w, acc[3][3]);
    }
    #pragma unroll
    for (int u = 0; u < 4; ++u) {
        float4 v = make_float4(fmaxf(acc[0][u], 0.f), fmaxf(acc[1][u], 0.f),
                               fmaxf(acc[2][u], 0.f), fmaxf(acc[3][u], 0.f));
        *(float4*)&out_rf[(size_t)(col0 + lc0 + u) * 256 + oH + o0] = v;
    }
}

extern "C" void kernel_launch(void* const* d_in, const int* in_sizes, int n_in,
                              void* d_out, int out_size, void* d_ws, size_t ws_size,
                              hipStream_t stream) {
    const float* xyz     = (const float*)d_in[0];
    const float* feature = (const float*)d_in[1];
    const float* new_xyz = (const float*)d_in[2];
    const int*   idx     = (const int*)  d_in[3];
    const float* weight  = (const float*)d_in[4];
    const float* conv_w  = (const float*)d_in[5];
    const float* conv_b  = (const float*)d_in[6];
    const float* mlp_w0  = (const float*)d_in[7];
    const float* mlp_b0  = (const float*)d_in[8];
    const float* mlp_w1  = (const float*)d_in[9];
    const float* mlp_b1  = (const float*)d_in[10];

    float* out    = (float*)d_out;
    float* out_rf = out + (size_t)B * M * 3;

    float* wsf = (float*)d_ws;
    __hip_bfloat16* xfh = (__hip_bfloat16*)wsf;  // 320000 bf16 (2 planes x 2 b)
    float* conv_wT = wsf + 160000;               // 13312
    float* xmidA   = conv_wT + 13312;            // B*M*128, [col][c]
    float* w0T     = xmidA + 1048576;            // 16384
    float* w1T     = w0T + 16384;                // 32768
    float* wsum    = w1T + 32768;                // 128
    // plane-1 conv partials live in out_rf's head (1 MB of its 8 MB):
    // written by gather, consumed by mlp0, then overwritten by mlp1.
    float* xmidB   = out_rf;

    {
        int total = 320000 + 13312 + 24576 + 16384 + 32768 + 128;
        int blocks = (total + 255) / 256;
        prep_kernel<<<blocks, 256, 0, stream>>>(xyz, feature, new_xyz, conv_w,
                                                mlp_w0, mlp_w1,
                                                xfh, conv_wT, w0T, w1T, wsum, out);
    }
    {
        int blocks = 2 * (S * B * M) / GPB;     // 512 = 256 group-sets x 2 planes
        gather_conv_kernel<<<blocks, NTH, 0, stream>>>(idx, weight, new_xyz,
                                                       (const uint2*)xfh,
                                                       conv_wT, conv_b, wsum,
                                                       xmidA, xmidB);
    }
    {
        mlp0_kernel<<<(B * M) / TC, 256, 0, stream>>>(xmidA, xmidB, w0T, mlp_b0);
    }
    {
        mlp1_kernel<<<2 * (B * M) / TC, 256, 0, stream>>>(xmidA, w1T, mlp_b1, out_rf);
    }
}